// Round 3
// baseline (863.257 us; speedup 1.0000x reference)
//
#include <hip/hip_runtime.h>
#include <hip/hip_bf16.h>

#define N_GENES 2000
#define SA 72
#define SH 136

typedef __attribute__((ext_vector_type(8))) short frag8;
typedef __attribute__((ext_vector_type(4))) float facc4;

static __device__ __forceinline__ unsigned short f2bf(float f) {
    unsigned int u = __float_as_uint(f);
    unsigned int r = (u + 0x7FFFu + ((u >> 16) & 1u)) >> 16;
    return (unsigned short)r;
}
static __device__ __forceinline__ float bf2f(unsigned short s) {
    return __uint_as_float(((unsigned int)s) << 16);
}
static __device__ __forceinline__ ushort2 pk2(float a, float b) {
    __hip_bfloat162 r = __float22bfloat162_rn(float2{a, b});
    return *(ushort2*)&r;
}

// ---- all weight transposes in one kernel; also zeroes deg[2N] ----
__global__ void prep(const float* __restrict__ ip_w,
                     const float* __restrict__ ws_f, const float* __restrict__ wd_f,
                     const float* __restrict__ ws_p, const float* __restrict__ wd_p,
                     unsigned short* __restrict__ Bt1,
                     unsigned short* __restrict__ Bf, unsigned short* __restrict__ Bp,
                     int* __restrict__ deg, int n2) {
    int idx = blockIdx.x * blockDim.x + threadIdx.x;
    if (idx < n2) deg[idx] = 0;
    if (idx < 128 * 2048) {
        int nrow = idx >> 11, k = idx & 2047;
        unsigned short v = 0;
        if (k < N_GENES) v = f2bf(ip_w[(size_t)k * 128 + nrow]);
        Bt1[idx] = v;
    } else {
        int q = idx - 128 * 2048;
        if (q >= 2 * 256 * 128) return;
        int g = q >> 15;
        int r = (q >> 7) & 255;
        int k = q & 127;
        const float* w = (g == 0) ? (r < 128 ? ws_f : wd_f) : (r < 128 ? ws_p : wd_p);
        (g == 0 ? Bf : Bp)[(r << 7) | k] = f2bf(w[k * 128 + (r & 127)]);
    }
}

// ---- fused GEMM: phase 1 h = fp32 A @ ip_w + b (bf16 MFMA, depth-2 A prefetch),
//      phase 2 per graph: [hs|hd] = h_tile @ B[256][128] written directly. ----
__global__ __launch_bounds__(256) void gemm_fused(const float* __restrict__ A,
                                                  const unsigned short* __restrict__ Bt,
                                                  const float* __restrict__ bias,
                                                  const unsigned short* __restrict__ Bf,
                                                  const unsigned short* __restrict__ Bp,
                                                  unsigned short* __restrict__ Cf,
                                                  unsigned short* __restrict__ Cp,
                                                  int M, int K) {
    const int Kpad = 2048;
    __shared__ __align__(16) unsigned short lA[64 * SA];
    __shared__ __align__(16) unsigned short lH[64 * SH];
    int t = threadIdx.x, lane = t & 63, wv = t >> 6;
    int lr = lane & 15, lq = lane >> 4;
    facc4 acc[4][2];
#pragma unroll
    for (int i = 0; i < 4; i++)
#pragma unroll
        for (int j = 0; j < 2; j++) acc[i][j] = (facc4){0.f, 0.f, 0.f, 0.f};
    int row_base = blockIdx.x * 64;

    // A staging coords: 16 threads per row, 16B each
    int ar_r[4], ar_c[4];
    const float* ar_p[4];
#pragma unroll
    for (int j = 0; j < 4; j++) {
        int q = j * 256 + t;
        ar_r[j] = q >> 4;
        ar_c[j] = (q & 15) * 4;
        int rg = row_base + ar_r[j];
        if (rg >= M) rg = M - 1;
        ar_p[j] = A + (size_t)rg * K + ar_c[j];
    }
    // B fragment pointers (col-major bf16 [128][2048], L2-resident)
    const unsigned short* bp[4];
#pragma unroll
    for (int ks = 0; ks < 2; ks++)
#pragma unroll
        for (int ni = 0; ni < 2; ni++) {
            int col = wv * 32 + ni * 16 + lr;
            bp[ks * 2 + ni] = Bt + (size_t)col * Kpad + ks * 32 + lq * 8;
        }

    // depth-2 A prefetch: arA holds k-step data about to be written, arB the next
    float4 arA[4], arB[4];
    frag8 bfr[4], bfn[4];
#pragma unroll
    for (int j = 0; j < 4; j++) arA[j] = *(const float4*)(ar_p[j]);
#pragma unroll
    for (int j = 0; j < 4; j++) arB[j] = *(const float4*)(ar_p[j] + 64);
#pragma unroll
    for (int f = 0; f < 4; f++) bfr[f] = *(const frag8*)(bp[f]);

    for (int k0 = 0; k0 < Kpad; k0 += 128) {
        // ---- even substep: k0 ----
        __syncthreads();
#pragma unroll
        for (int j = 0; j < 4; j++) {
            ushort2 u01 = pk2(arA[j].x, arA[j].y);
            ushort2 u23 = pk2(arA[j].z, arA[j].w);
            ushort4 u = {u01.x, u01.y, u23.x, u23.y};
            *(ushort4*)&lA[ar_r[j] * SA + ar_c[j]] = u;
        }
        int ka = k0 + 128;
        if (ka < Kpad) {
#pragma unroll
            for (int j = 0; j < 4; j++) {
                int kk = ka + ar_c[j];
                float4 v = {0.f, 0.f, 0.f, 0.f};
                if (kk < K) v = *(const float4*)(ar_p[j] + ka);
                arA[j] = v;
            }
        }
        __syncthreads();
#pragma unroll
        for (int f = 0; f < 4; f++) bfn[f] = *(const frag8*)(bp[f] + k0 + 64);
#pragma unroll
        for (int ks = 0; ks < 2; ks++) {
            frag8 af[4];
#pragma unroll
            for (int mi = 0; mi < 4; mi++)
                af[mi] = *(const frag8*)&lA[(mi * 16 + lr) * SA + ks * 32 + lq * 8];
#pragma unroll
            for (int mi = 0; mi < 4; mi++)
#pragma unroll
                for (int ni = 0; ni < 2; ni++)
                    acc[mi][ni] = __builtin_amdgcn_mfma_f32_16x16x32_bf16(af[mi], bfr[ks * 2 + ni], acc[mi][ni], 0, 0, 0);
        }
        // ---- odd substep: k0 + 64 ----
        __syncthreads();
#pragma unroll
        for (int j = 0; j < 4; j++) {
            ushort2 u01 = pk2(arB[j].x, arB[j].y);
            ushort2 u23 = pk2(arB[j].z, arB[j].w);
            ushort4 u = {u01.x, u01.y, u23.x, u23.y};
            *(ushort4*)&lA[ar_r[j] * SA + ar_c[j]] = u;
        }
        int kb = k0 + 192;
        if (kb < Kpad) {
#pragma unroll
            for (int j = 0; j < 4; j++) {
                int kk = kb + ar_c[j];
                float4 v = {0.f, 0.f, 0.f, 0.f};
                if (kk < K) v = *(const float4*)(ar_p[j] + kb);
                arB[j] = v;
            }
        }
        __syncthreads();
        if (ka < Kpad) {
#pragma unroll
            for (int f = 0; f < 4; f++) bfr[f] = *(const frag8*)(bp[f] + ka);
        }
#pragma unroll
        for (int ks = 0; ks < 2; ks++) {
            frag8 af[4];
#pragma unroll
            for (int mi = 0; mi < 4; mi++)
                af[mi] = *(const frag8*)&lA[(mi * 16 + lr) * SA + ks * 32 + lq * 8];
#pragma unroll
            for (int mi = 0; mi < 4; mi++)
#pragma unroll
                for (int ni = 0; ni < 2; ni++)
                    acc[mi][ni] = __builtin_amdgcn_mfma_f32_16x16x32_bf16(af[mi], bfn[ks * 2 + ni], acc[mi][ni], 0, 0, 0);
        }
    }
    // phase-1 epilogue: h tile (bias added) -> LDS bf16
    __syncthreads();
#pragma unroll
    for (int mi = 0; mi < 4; mi++) {
#pragma unroll
        for (int r = 0; r < 4; r++) {
            int row = mi * 16 + lq * 4 + r;
#pragma unroll
            for (int ni = 0; ni < 2; ni++) {
                int col = wv * 32 + ni * 16 + lr;
                lH[row * SH + col] = f2bf(acc[mi][ni][r] + bias[col]);
            }
        }
    }
    __syncthreads();
    // phase 2: per graph, [hs|hd] tile = lH(64x128) @ B^T(128x256)
#pragma unroll 1
    for (int g = 0; g < 2; g++) {
        const unsigned short* B2 = g ? Bp : Bf;
        unsigned short* Cb = g ? Cp : Cf;
        facc4 a2[4][4];
#pragma unroll
        for (int i = 0; i < 4; i++)
#pragma unroll
            for (int j = 0; j < 4; j++) a2[i][j] = (facc4){0.f, 0.f, 0.f, 0.f};
#pragma unroll
        for (int ks = 0; ks < 4; ks++) {
            frag8 af[4], bf[4];
#pragma unroll
            for (int mi = 0; mi < 4; mi++)
                af[mi] = *(const frag8*)&lH[(mi * 16 + lr) * SH + ks * 32 + lq * 8];
#pragma unroll
            for (int ni = 0; ni < 4; ni++)
                bf[ni] = *(const frag8*)(B2 + ((wv * 64 + ni * 16 + lr) << 7) + ks * 32 + lq * 8);
#pragma unroll
            for (int mi = 0; mi < 4; mi++)
#pragma unroll
                for (int ni = 0; ni < 4; ni++)
                    a2[mi][ni] = __builtin_amdgcn_mfma_f32_16x16x32_bf16(af[mi], bf[ni], a2[mi][ni], 0, 0, 0);
        }
#pragma unroll
        for (int mi = 0; mi < 4; mi++) {
#pragma unroll
            for (int r = 0; r < 4; r++) {
                int row = row_base + mi * 16 + lq * 4 + r;
                if (row < M) {
#pragma unroll
                    for (int ni = 0; ni < 4; ni++) {
                        int col = wv * 64 + ni * 16 + lr;
                        Cb[(size_t)row * 256 + col] = f2bf(a2[mi][ni][r]);
                    }
                }
            }
        }
    }
}

// ---- degree histogram for both graphs into deg[2N] ----
__global__ void deg2(const int* __restrict__ dst_f, int Ef,
                     const int* __restrict__ dst_p, int Ep,
                     int* __restrict__ deg, int N) {
    int e = blockIdx.x * blockDim.x + threadIdx.x;
    if (e < Ef) atomicAdd(&deg[dst_f[e]], 1);
    else if (e < Ef + Ep) atomicAdd(&deg[N + dst_p[e - Ef]], 1);
}

// ---- hierarchical exclusive scan ----
__global__ __launch_bounds__(256) void scan_part(const int* __restrict__ in,
                                                 int* __restrict__ bsum, int n) {
    int t = threadIdx.x, b = blockIdx.x;
    int lane = t & 63, wv = t >> 6;
    int base = b * 2048 + t * 8;
    int s = 0;
    if (base + 7 < n) {
        int4 v0 = *(const int4*)(in + base);
        int4 v1 = *(const int4*)(in + base + 4);
        s = v0.x + v0.y + v0.z + v0.w + v1.x + v1.y + v1.z + v1.w;
    } else {
#pragma unroll
        for (int j = 0; j < 8; j++) if (base + j < n) s += in[base + j];
    }
#pragma unroll
    for (int o = 32; o >= 1; o >>= 1) s += __shfl_xor(s, o);
    __shared__ int red[4];
    if (lane == 0) red[wv] = s;
    __syncthreads();
    if (t == 0) bsum[b] = red[0] + red[1] + red[2] + red[3];
}

__global__ __launch_bounds__(256) void scan_tops(int* __restrict__ bsum, int nb,
                                                 int* __restrict__ offs, int n) {
    __shared__ int buf[256];
    int t = threadIdx.x;
    int orig = (t < nb) ? bsum[t] : 0;
    int v = orig;
    buf[t] = v;
    __syncthreads();
    for (int o = 1; o < 256; o <<= 1) {
        int y = (t >= o) ? buf[t - o] : 0;
        __syncthreads();
        v += y;
        buf[t] = v;
        __syncthreads();
    }
    if (t < nb) bsum[t] = v - orig;
    if (t == nb - 1) offs[n] = v;
}

__global__ __launch_bounds__(256) void scan_final(const int* __restrict__ in,
                                                  const int* __restrict__ bsum,
                                                  int* __restrict__ offs, int n) {
    int t = threadIdx.x, b = blockIdx.x;
    int lane = t & 63, wv = t >> 6;
    int base = b * 2048 + t * 8;
    int a[8];
#pragma unroll
    for (int j = 0; j < 8; j++) a[j] = (base + j < n) ? in[base + j] : 0;
    int s = a[0] + a[1] + a[2] + a[3] + a[4] + a[5] + a[6] + a[7];
    int incl = s;
#pragma unroll
    for (int o = 1; o < 64; o <<= 1) {
        int y = __shfl_up(incl, o);
        if (lane >= o) incl += y;
    }
    __shared__ int wsum[4];
    if (lane == 63) wsum[wv] = incl;
    __syncthreads();
    int wpre = 0;
#pragma unroll
    for (int j = 0; j < 4; j++) if (j < wv) wpre += wsum[j];
    int excl = incl - s + wpre + bsum[b];
#pragma unroll
    for (int j = 0; j < 8; j++) {
        if (base + j < n) offs[base + j] = excl;
        excl += a[j];
    }
}

// ---- fill CSR-ordered (src, weight) int2 pairs; decrements deg in place ----
__global__ void fill2(const int* __restrict__ src_f, const int* __restrict__ dst_f,
                      const float* __restrict__ ew_f, int Ef,
                      const int* __restrict__ src_p, const int* __restrict__ dst_p,
                      const float* __restrict__ ew_p, int Ep,
                      const int* __restrict__ offs, int* __restrict__ deg,
                      int2* __restrict__ srcw, int N) {
    int e = blockIdx.x * blockDim.x + threadIdx.x;
    if (e >= Ef + Ep) return;
    int g = (e >= Ef);
    int ee = g ? e - Ef : e;
    int d = g ? dst_p[ee] : dst_f[ee];
    int node = g ? N + d : d;
    int p = offs[node] + atomicAdd(&deg[node], -1) - 1;
    int s = g ? src_p[ee] : src_f[ee];
    float w = g ? ew_p[ee] : ew_f[ee];
    srcw[p] = make_int2(s, __float_as_int(w));
}

// ---- GAT: one wave per dst node, 2 dims/lane (head = 16-lane group). ----
__global__ __launch_bounds__(256) void gat2(const int* __restrict__ offs,
                                            const int2* __restrict__ srcw,
                                            const unsigned short* __restrict__ hshd_f,
                                            const unsigned short* __restrict__ hshd_p,
                                            const float* __restrict__ wedge_f,
                                            const float* __restrict__ attn_f,
                                            const float* __restrict__ bias_f,
                                            const float* __restrict__ wedge_p,
                                            const float* __restrict__ attn_p,
                                            const float* __restrict__ bias_p,
                                            float* __restrict__ out_full,
                                            float* __restrict__ out_pruned, int N) {
    int node = blockIdx.x * 4 + (threadIdx.x >> 6);
    if (node >= 2 * N) return;
    int g = node >= N;
    int onode = g ? node - N : node;
    const unsigned short* hshd = g ? hshd_p : hshd_f;
    const float* wedge = g ? wedge_p : wedge_f;
    const float* attn = g ? attn_p : attn_f;
    const float* bias = g ? bias_p : bias_f;
    float* out = g ? out_pruned : out_full;
    int lane = threadIdx.x & 63;
    int d2 = lane * 2;  // lane owns dims d2, d2+1
    const float LOG2E = 1.4426950408889634f;
    const float2 wv = *(const float2*)&wedge[d2];
    float2 av = *(const float2*)&attn[d2];
    av.x *= LOG2E; av.y *= LOG2E;
    unsigned int hdraw = *(const unsigned int*)&hshd[(size_t)onode * 256 + 128 + d2];
    const float hd0 = __uint_as_float(hdraw << 16);
    const float hd1 = __uint_as_float(hdraw & 0xffff0000u);
    int s = offs[node], cnt = offs[node + 1] - s;
    float m = -INFINITY, l = 0.f, acc0 = 0.f, acc1 = 0.f;
    if (cnt > 0) {
        int last = s + cnt - 1;
        auto CL = [last](int j) { return j > last ? last : j; };
        int2 e0 = srcw[s], e1 = srcw[CL(s + 1)], e2 = srcw[CL(s + 2)], e3 = srcw[CL(s + 3)];
        int2 e4 = srcw[CL(s + 4)], e5 = srcw[CL(s + 5)], e6 = srcw[CL(s + 6)], e7 = srcw[CL(s + 7)];
        int2 e8 = srcw[CL(s + 8)], e9 = srcw[CL(s + 9)];
        unsigned int hr0 = *(const unsigned int*)&hshd[(size_t)e0.x * 256 + d2];
        unsigned int hr1 = *(const unsigned int*)&hshd[(size_t)e1.x * 256 + d2];
        unsigned int hr2 = *(const unsigned int*)&hshd[(size_t)e2.x * 256 + d2];
        unsigned int hr3 = *(const unsigned int*)&hshd[(size_t)e3.x * 256 + d2];
        unsigned int hr4 = *(const unsigned int*)&hshd[(size_t)e4.x * 256 + d2];
        unsigned int hr5 = *(const unsigned int*)&hshd[(size_t)e5.x * 256 + d2];
        for (int i = 0; i < cnt; i += 2) {
            int2 ea = srcw[CL(s + i + 10)], eb = srcw[CL(s + i + 11)];
            unsigned int hr6 = *(const unsigned int*)&hshd[(size_t)e6.x * 256 + d2];
            unsigned int hr7 = *(const unsigned int*)&hshd[(size_t)e7.x * 256 + d2];
            {
                float h0 = __uint_as_float(hr0 << 16);
                float h1 = __uint_as_float(hr0 & 0xffff0000u);
                float w = __int_as_float(e0.y);
                float z0 = fmaf(w, wv.x, h0 + hd0); z0 = (z0 > 0.f) ? z0 : 0.2f * z0;
                float z1 = fmaf(w, wv.y, h1 + hd1); z1 = (z1 > 0.f) ? z1 : 0.2f * z1;
                float t = z0 * av.x + z1 * av.y;
                t += __shfl_xor(t, 1);
                t += __shfl_xor(t, 2);
                t += __shfl_xor(t, 4);
                t += __shfl_xor(t, 8);
                float mn = fmaxf(m, t);
                float sc = __builtin_amdgcn_exp2f(m - mn);
                float p = __builtin_amdgcn_exp2f(t - mn);
                l = l * sc + p;
                acc0 = acc0 * sc + p * h0;
                acc1 = acc1 * sc + p * h1;
                m = mn;
            }
            if (i + 1 < cnt) {
                float h0 = __uint_as_float(hr1 << 16);
                float h1 = __uint_as_float(hr1 & 0xffff0000u);
                float w = __int_as_float(e1.y);
                float z0 = fmaf(w, wv.x, h0 + hd0); z0 = (z0 > 0.f) ? z0 : 0.2f * z0;
                float z1 = fmaf(w, wv.y, h1 + hd1); z1 = (z1 > 0.f) ? z1 : 0.2f * z1;
                float t = z0 * av.x + z1 * av.y;
                t += __shfl_xor(t, 1);
                t += __shfl_xor(t, 2);
                t += __shfl_xor(t, 4);
                t += __shfl_xor(t, 8);
                float mn = fmaxf(m, t);
                float sc = __builtin_amdgcn_exp2f(m - mn);
                float p = __builtin_amdgcn_exp2f(t - mn);
                l = l * sc + p;
                acc0 = acc0 * sc + p * h0;
                acc1 = acc1 * sc + p * h1;
                m = mn;
            }
            e0 = e2; e1 = e3; e2 = e4; e3 = e5; e4 = e6; e5 = e7; e6 = e8; e7 = e9; e8 = ea; e9 = eb;
            hr0 = hr2; hr1 = hr3; hr2 = hr4; hr3 = hr5; hr4 = hr6; hr5 = hr7;
        }
    }
    float inv = 1.f / (l + 1e-16f);
    const float2 bv = *(const float2*)&bias[d2];
    float2 o;
    o.x = acc0 * inv + bv.x;
    o.y = acc1 * inv + bv.y;
    *(float2*)&out[(size_t)onode * 128 + d2] = o;
}

// ---- combine + ELU + LayerNorm (in-place on d_out holding h_pruned), 2 dims/lane ----
__global__ __launch_bounds__(256) void final_kernel(const float* __restrict__ hf,
                                                    float* __restrict__ out,
                                                    const float* __restrict__ alpha_p,
                                                    const float* __restrict__ scale,
                                                    const float* __restrict__ beta, int n) {
    int node = blockIdx.x * 4 + (threadIdx.x >> 6);
    if (node >= n) return;
    int lane = threadIdx.x & 63;
    int d2 = lane * 2;
    float a = *alpha_p;
    float2 f = *(const float2*)&hf[(size_t)node * 128 + d2];
    float2 p = *(const float2*)&out[(size_t)node * 128 + d2];
    float x0 = (1.f - a) * f.x + a * p.x;
    float x1 = (1.f - a) * f.y + a * p.y;
    x0 = (x0 > 0.f) ? x0 : expm1f(x0);
    x1 = (x1 > 0.f) ? x1 : expm1f(x1);
    float sm = x0 + x1;
#pragma unroll
    for (int o = 32; o >= 1; o >>= 1) sm += __shfl_xor(sm, o);
    float mu = sm * (1.f / 128.f);
    float d0 = x0 - mu, d1 = x1 - mu;
    float v = d0 * d0 + d1 * d1;
#pragma unroll
    for (int o = 32; o >= 1; o >>= 1) v += __shfl_xor(v, o);
    float rstd = rsqrtf(v * (1.f / 128.f) + 1e-6f);
    const float2 sv = *(const float2*)&scale[d2];
    const float2 bv = *(const float2*)&beta[d2];
    float2 o2;
    o2.x = d0 * rstd * sv.x + bv.x;
    o2.y = d1 * rstd * sv.y + bv.y;
    *(float2*)&out[(size_t)node * 128 + d2] = o2;
}

extern "C" void kernel_launch(void* const* d_in, const int* in_sizes, int n_in,
                              void* d_out, int out_size, void* d_ws, size_t ws_size,
                              hipStream_t stream) {
    const float* nf = (const float*)d_in[0];
    const int* fei = (const int*)d_in[1];
    const float* few = (const float*)d_in[2];
    const int* pei = (const int*)d_in[3];
    const float* pew = (const float*)d_in[4];
    const float* alpha = (const float*)d_in[5];
    const float* ip_w = (const float*)d_in[6];
    const float* ip_b = (const float*)d_in[7];
    const float* gf_wsrc = (const float*)d_in[8];
    const float* gf_wdst = (const float*)d_in[9];
    const float* gf_wedge = (const float*)d_in[10];
    const float* gf_attn = (const float*)d_in[11];
    const float* gf_bias = (const float*)d_in[12];
    const float* gp_wsrc = (const float*)d_in[13];
    const float* gp_wdst = (const float*)d_in[14];
    const float* gp_wedge = (const float*)d_in[15];
    const float* gp_attn = (const float*)d_in[16];
    const float* gp_bias = (const float*)d_in[17];
    const float* ln_scale = (const float*)d_in[18];
    const float* ln_bias = (const float*)d_in[19];

    const int N = in_sizes[0] / N_GENES;
    const int Ef = in_sizes[1] / 2;
    const int Ep = in_sizes[3] / 2;
    const int Etot = Ef + Ep;
    const int n2 = 2 * N;

    char* base = (char*)d_ws;
    size_t off = 0;
    auto carve = [&](size_t bytes) -> char* {
        char* p = base + off;
        off = (off + bytes + 255) & ~(size_t)255;
        return p;
    };
    unsigned short* Bt1 = (unsigned short*)carve((size_t)128 * 2048 * 2);
    unsigned short* Bf = (unsigned short*)carve(256 * 128 * 2);
    unsigned short* Bp = (unsigned short*)carve(256 * 128 * 2);
    unsigned short* hshd_f = (unsigned short*)carve((size_t)N * 256 * 2);
    unsigned short* hshd_p = (unsigned short*)carve((size_t)N * 256 * 2);
    float* h_full = (float*)carve((size_t)N * 128 * 4);
    int* deg = (int*)carve((size_t)n2 * 4);
    int* offs = (int*)carve((size_t)(n2 + 4) * 4);
    int* bsum = (int*)carve(256 * 4);
    int2* srcw = (int2*)carve((size_t)Etot * 8);
    float* out_f = (float*)d_out;

    prep<<<(128 * 2048 + 2 * 256 * 128 + 255) / 256, 256, 0, stream>>>(
        ip_w, gf_wsrc, gf_wdst, gp_wsrc, gp_wdst, Bt1, Bf, Bp, deg, n2);

    int gb1 = (N + 63) / 64;
    gemm_fused<<<gb1, 256, 0, stream>>>(nf, Bt1, ip_b, Bf, Bp, hshd_f, hshd_p, N, N_GENES);

    const int* src_f = fei;
    const int* dst_f = fei + Ef;
    const int* src_p = pei;
    const int* dst_p = pei + Ep;
    deg2<<<(Etot + 255) / 256, 256, 0, stream>>>(dst_f, Ef, dst_p, Ep, deg, N);
    int nb = (n2 + 2047) / 2048;
    scan_part<<<nb, 256, 0, stream>>>(deg, bsum, n2);
    scan_tops<<<1, 256, 0, stream>>>(bsum, nb, offs, n2);
    scan_final<<<nb, 256, 0, stream>>>(deg, bsum, offs, n2);
    fill2<<<(Etot + 255) / 256, 256, 0, stream>>>(src_f, dst_f, few, Ef, src_p, dst_p, pew, Ep,
                                                  offs, deg, srcw, N);

    gat2<<<(n2 + 3) / 4, 256, 0, stream>>>(offs, srcw, hshd_f, hshd_p,
                                           gf_wedge, gf_attn, gf_bias,
                                           gp_wedge, gp_attn, gp_bias,
                                           h_full, out_f, N);

    final_kernel<<<(N + 3) / 4, 256, 0, stream>>>(h_full, out_f, alpha, ln_scale, ln_bias, N);
    (void)ws_size; (void)n_in; (void)out_size;
}

// Round 4
// 813.112 us; speedup vs baseline: 1.0617x; 1.0617x over previous
//
#include <hip/hip_runtime.h>
#include <hip/hip_bf16.h>

#define N_GENES 2000
#define SA 72
#define SH 136

typedef __attribute__((ext_vector_type(8))) short frag8;
typedef __attribute__((ext_vector_type(4))) float facc4;

static __device__ __forceinline__ unsigned short f2bf(float f) {
    unsigned int u = __float_as_uint(f);
    unsigned int r = (u + 0x7FFFu + ((u >> 16) & 1u)) >> 16;
    return (unsigned short)r;
}
static __device__ __forceinline__ float bf2f(unsigned short s) {
    return __uint_as_float(((unsigned int)s) << 16);
}
static __device__ __forceinline__ ushort2 pk2(float a, float b) {
    __hip_bfloat162 r = __float22bfloat162_rn(float2{a, b});
    return *(ushort2*)&r;
}

// ---- all weight transposes in one kernel; also zeroes deg[2N] ----
__global__ void prep(const float* __restrict__ ip_w,
                     const float* __restrict__ ws_f, const float* __restrict__ wd_f,
                     const float* __restrict__ ws_p, const float* __restrict__ wd_p,
                     unsigned short* __restrict__ Bt1,
                     unsigned short* __restrict__ Bf, unsigned short* __restrict__ Bp,
                     int* __restrict__ deg, int n2) {
    int idx = blockIdx.x * blockDim.x + threadIdx.x;
    if (idx < n2) deg[idx] = 0;
    if (idx < 128 * 2048) {
        int nrow = idx >> 11, k = idx & 2047;
        unsigned short v = 0;
        if (k < N_GENES) v = f2bf(ip_w[(size_t)k * 128 + nrow]);
        Bt1[idx] = v;
    } else {
        int q = idx - 128 * 2048;
        if (q >= 2 * 256 * 128) return;
        int g = q >> 15;
        int r = (q >> 7) & 255;
        int k = q & 127;
        const float* w = (g == 0) ? (r < 128 ? ws_f : wd_f) : (r < 128 ? ws_p : wd_p);
        (g == 0 ? Bf : Bp)[(r << 7) | k] = f2bf(w[k * 128 + (r & 127)]);
    }
}

// ---- mega dispatch: blocks [0,gemmBlocks) run the fused GEMM;
//      blocks [gemmBlocks,..) run the degree histogram (independent work,
//      hidden under the GEMM's DMA phase). ----
__global__ __launch_bounds__(256) void gemm_deg(const float* __restrict__ A,
                                                const unsigned short* __restrict__ Bt,
                                                const float* __restrict__ bias,
                                                const unsigned short* __restrict__ Bf,
                                                const unsigned short* __restrict__ Bp,
                                                unsigned short* __restrict__ Cf,
                                                unsigned short* __restrict__ Cp,
                                                int M, int K, int gemmBlocks,
                                                const int* __restrict__ dst_f, int Ef,
                                                const int* __restrict__ dst_p, int Ep,
                                                int* __restrict__ deg, int N) {
    if (blockIdx.x >= gemmBlocks) {
        int e = (blockIdx.x - gemmBlocks) * 256 + threadIdx.x;
        if (e < Ef) atomicAdd(&deg[dst_f[e]], 1);
        else if (e < Ef + Ep) atomicAdd(&deg[N + dst_p[e - Ef]], 1);
        return;
    }
    const int Kpad = 2048;
    __shared__ __align__(16) unsigned short lA[64 * SA];
    __shared__ __align__(16) unsigned short lH[64 * SH];
    int t = threadIdx.x, lane = t & 63, wv = t >> 6;
    int lr = lane & 15, lq = lane >> 4;
    facc4 acc[4][2];
#pragma unroll
    for (int i = 0; i < 4; i++)
#pragma unroll
        for (int j = 0; j < 2; j++) acc[i][j] = (facc4){0.f, 0.f, 0.f, 0.f};
    int row_base = blockIdx.x * 64;

    // A staging coords: 16 threads per row, 16B each
    int ar_r[4], ar_c[4];
    const float* ar_p[4];
#pragma unroll
    for (int j = 0; j < 4; j++) {
        int q = j * 256 + t;
        ar_r[j] = q >> 4;
        ar_c[j] = (q & 15) * 4;
        int rg = row_base + ar_r[j];
        if (rg >= M) rg = M - 1;
        ar_p[j] = A + (size_t)rg * K + ar_c[j];
    }
    // B fragment pointers (col-major bf16 [128][2048], L2-resident)
    const unsigned short* bp[4];
#pragma unroll
    for (int ks = 0; ks < 2; ks++)
#pragma unroll
        for (int ni = 0; ni < 2; ni++) {
            int col = wv * 32 + ni * 16 + lr;
            bp[ks * 2 + ni] = Bt + (size_t)col * Kpad + ks * 32 + lq * 8;
        }

    float4 ar[4];
    frag8 bfr[4];
#pragma unroll
    for (int j = 0; j < 4; j++) ar[j] = *(const float4*)(ar_p[j]);
#pragma unroll
    for (int f = 0; f < 4; f++) bfr[f] = *(const frag8*)(bp[f]);

    for (int k0 = 0; k0 < Kpad; k0 += 64) {
        __syncthreads();
#pragma unroll
        for (int j = 0; j < 4; j++) {
            ushort2 u01 = pk2(ar[j].x, ar[j].y);
            ushort2 u23 = pk2(ar[j].z, ar[j].w);
            ushort4 u = {u01.x, u01.y, u23.x, u23.y};
            *(ushort4*)&lA[ar_r[j] * SA + ar_c[j]] = u;
        }
        __syncthreads();
        int kn = k0 + 64;
        frag8 bfn[4];
        if (kn < Kpad) {
#pragma unroll
            for (int j = 0; j < 4; j++) {
                int kk = kn + ar_c[j];
                float4 v = {0.f, 0.f, 0.f, 0.f};
                if (kk < K) v = *(const float4*)(ar_p[j] + kn);
                ar[j] = v;
            }
#pragma unroll
            for (int f = 0; f < 4; f++) bfn[f] = *(const frag8*)(bp[f] + kn);
        }
#pragma unroll
        for (int ks = 0; ks < 2; ks++) {
            frag8 af[4];
#pragma unroll
            for (int mi = 0; mi < 4; mi++)
                af[mi] = *(const frag8*)&lA[(mi * 16 + lr) * SA + ks * 32 + lq * 8];
#pragma unroll
            for (int mi = 0; mi < 4; mi++)
#pragma unroll
                for (int ni = 0; ni < 2; ni++)
                    acc[mi][ni] = __builtin_amdgcn_mfma_f32_16x16x32_bf16(af[mi], bfr[ks * 2 + ni], acc[mi][ni], 0, 0, 0);
        }
        if (kn < Kpad) {
#pragma unroll
            for (int f = 0; f < 4; f++) bfr[f] = bfn[f];
        }
    }
    // phase-1 epilogue: h tile (bias added) -> LDS bf16
    __syncthreads();
#pragma unroll
    for (int mi = 0; mi < 4; mi++) {
#pragma unroll
        for (int r = 0; r < 4; r++) {
            int row = mi * 16 + lq * 4 + r;
#pragma unroll
            for (int ni = 0; ni < 2; ni++) {
                int col = wv * 32 + ni * 16 + lr;
                lH[row * SH + col] = f2bf(acc[mi][ni][r] + bias[col]);
            }
        }
    }
    __syncthreads();
    // phase 2: per graph, [hs|hd] tile = lH(64x128) @ B^T(128x256)
#pragma unroll 1
    for (int g = 0; g < 2; g++) {
        const unsigned short* B2 = g ? Bp : Bf;
        unsigned short* Cb = g ? Cp : Cf;
        facc4 a2[4][4];
#pragma unroll
        for (int i = 0; i < 4; i++)
#pragma unroll
            for (int j = 0; j < 4; j++) a2[i][j] = (facc4){0.f, 0.f, 0.f, 0.f};
#pragma unroll
        for (int ks = 0; ks < 4; ks++) {
            frag8 af[4], bf[4];
#pragma unroll
            for (int mi = 0; mi < 4; mi++)
                af[mi] = *(const frag8*)&lH[(mi * 16 + lr) * SH + ks * 32 + lq * 8];
#pragma unroll
            for (int ni = 0; ni < 4; ni++)
                bf[ni] = *(const frag8*)(B2 + ((wv * 64 + ni * 16 + lr) << 7) + ks * 32 + lq * 8);
#pragma unroll
            for (int mi = 0; mi < 4; mi++)
#pragma unroll
                for (int ni = 0; ni < 4; ni++)
                    a2[mi][ni] = __builtin_amdgcn_mfma_f32_16x16x32_bf16(af[mi], bf[ni], a2[mi][ni], 0, 0, 0);
        }
#pragma unroll
        for (int mi = 0; mi < 4; mi++) {
#pragma unroll
            for (int r = 0; r < 4; r++) {
                int row = row_base + mi * 16 + lq * 4 + r;
                if (row < M) {
#pragma unroll
                    for (int ni = 0; ni < 4; ni++) {
                        int col = wv * 64 + ni * 16 + lr;
                        Cb[(size_t)row * 256 + col] = f2bf(a2[mi][ni][r]);
                    }
                }
            }
        }
    }
}

// ---- hierarchical exclusive scan ----
__global__ __launch_bounds__(256) void scan_part(const int* __restrict__ in,
                                                 int* __restrict__ bsum, int n) {
    int t = threadIdx.x, b = blockIdx.x;
    int lane = t & 63, wv = t >> 6;
    int base = b * 2048 + t * 8;
    int s = 0;
    if (base + 7 < n) {
        int4 v0 = *(const int4*)(in + base);
        int4 v1 = *(const int4*)(in + base + 4);
        s = v0.x + v0.y + v0.z + v0.w + v1.x + v1.y + v1.z + v1.w;
    } else {
#pragma unroll
        for (int j = 0; j < 8; j++) if (base + j < n) s += in[base + j];
    }
#pragma unroll
    for (int o = 32; o >= 1; o >>= 1) s += __shfl_xor(s, o);
    __shared__ int red[4];
    if (lane == 0) red[wv] = s;
    __syncthreads();
    if (t == 0) bsum[b] = red[0] + red[1] + red[2] + red[3];
}

__global__ __launch_bounds__(256) void scan_tops(int* __restrict__ bsum, int nb,
                                                 int* __restrict__ offs, int n) {
    __shared__ int buf[256];
    int t = threadIdx.x;
    int orig = (t < nb) ? bsum[t] : 0;
    int v = orig;
    buf[t] = v;
    __syncthreads();
    for (int o = 1; o < 256; o <<= 1) {
        int y = (t >= o) ? buf[t - o] : 0;
        __syncthreads();
        v += y;
        buf[t] = v;
        __syncthreads();
    }
    if (t < nb) bsum[t] = v - orig;
    if (t == nb - 1) offs[n] = v;
}

__global__ __launch_bounds__(256) void scan_final(const int* __restrict__ in,
                                                  const int* __restrict__ bsum,
                                                  int* __restrict__ offs, int n) {
    int t = threadIdx.x, b = blockIdx.x;
    int lane = t & 63, wv = t >> 6;
    int base = b * 2048 + t * 8;
    int a[8];
#pragma unroll
    for (int j = 0; j < 8; j++) a[j] = (base + j < n) ? in[base + j] : 0;
    int s = a[0] + a[1] + a[2] + a[3] + a[4] + a[5] + a[6] + a[7];
    int incl = s;
#pragma unroll
    for (int o = 1; o < 64; o <<= 1) {
        int y = __shfl_up(incl, o);
        if (lane >= o) incl += y;
    }
    __shared__ int wsum[4];
    if (lane == 63) wsum[wv] = incl;
    __syncthreads();
    int wpre = 0;
#pragma unroll
    for (int j = 0; j < 4; j++) if (j < wv) wpre += wsum[j];
    int excl = incl - s + wpre + bsum[b];
#pragma unroll
    for (int j = 0; j < 8; j++) {
        if (base + j < n) offs[base + j] = excl;
        excl += a[j];
    }
}

// ---- fill CSR-ordered (src, weight) int2 pairs; decrements deg in place ----
__global__ void fill2(const int* __restrict__ src_f, const int* __restrict__ dst_f,
                      const float* __restrict__ ew_f, int Ef,
                      const int* __restrict__ src_p, const int* __restrict__ dst_p,
                      const float* __restrict__ ew_p, int Ep,
                      const int* __restrict__ offs, int* __restrict__ deg,
                      int2* __restrict__ srcw, int N) {
    int e = blockIdx.x * blockDim.x + threadIdx.x;
    if (e >= Ef + Ep) return;
    int g = (e >= Ef);
    int ee = g ? e - Ef : e;
    int d = g ? dst_p[ee] : dst_f[ee];
    int node = g ? N + d : d;
    int p = offs[node] + atomicAdd(&deg[node], -1) - 1;
    int s = g ? src_p[ee] : src_f[ee];
    float w = g ? ew_p[ee] : ew_f[ee];
    srcw[p] = make_int2(s, __float_as_int(w));
}

// ---- GAT: one wave per dst node, 2 dims/lane (head = 16-lane group).
//      6/4-deep pipeline (srcw 4-5 ahead, gathers 2-iter slack) — deeper proved null (R1),
//      shallower cuts redundant clamped issue for the avg-12-edge node. ----
__global__ __launch_bounds__(256) void gat2(const int* __restrict__ offs,
                                            const int2* __restrict__ srcw,
                                            const unsigned short* __restrict__ hshd_f,
                                            const unsigned short* __restrict__ hshd_p,
                                            const float* __restrict__ wedge_f,
                                            const float* __restrict__ attn_f,
                                            const float* __restrict__ bias_f,
                                            const float* __restrict__ wedge_p,
                                            const float* __restrict__ attn_p,
                                            const float* __restrict__ bias_p,
                                            float* __restrict__ out_full,
                                            float* __restrict__ out_pruned, int N) {
    int node = blockIdx.x * 4 + (threadIdx.x >> 6);
    if (node >= 2 * N) return;
    int g = node >= N;
    int onode = g ? node - N : node;
    const unsigned short* hshd = g ? hshd_p : hshd_f;
    const float* wedge = g ? wedge_p : wedge_f;
    const float* attn = g ? attn_p : attn_f;
    const float* bias = g ? bias_p : bias_f;
    float* out = g ? out_pruned : out_full;
    int lane = threadIdx.x & 63;
    int d2 = lane * 2;  // lane owns dims d2, d2+1
    const float LOG2E = 1.4426950408889634f;
    const float2 wv = *(const float2*)&wedge[d2];
    float2 av = *(const float2*)&attn[d2];
    av.x *= LOG2E; av.y *= LOG2E;
    unsigned int hdraw = *(const unsigned int*)&hshd[(size_t)onode * 256 + 128 + d2];
    const float hd0 = __uint_as_float(hdraw << 16);
    const float hd1 = __uint_as_float(hdraw & 0xffff0000u);
    int s = offs[node], cnt = offs[node + 1] - s;
    float m = -INFINITY, l = 0.f, acc0 = 0.f, acc1 = 0.f;
    if (cnt > 0) {
        int last = s + cnt - 1;
        auto CL = [last](int j) { return j > last ? last : j; };
        int2 e0 = srcw[s], e1 = srcw[CL(s + 1)], e2 = srcw[CL(s + 2)], e3 = srcw[CL(s + 3)];
        int2 e4 = srcw[CL(s + 4)], e5 = srcw[CL(s + 5)];
        unsigned int hr0 = *(const unsigned int*)&hshd[(size_t)e0.x * 256 + d2];
        unsigned int hr1 = *(const unsigned int*)&hshd[(size_t)e1.x * 256 + d2];
        unsigned int hr2 = *(const unsigned int*)&hshd[(size_t)e2.x * 256 + d2];
        unsigned int hr3 = *(const unsigned int*)&hshd[(size_t)e3.x * 256 + d2];
        for (int i = 0; i < cnt; i += 2) {
            int2 ea = srcw[CL(s + i + 6)], eb = srcw[CL(s + i + 7)];
            unsigned int hr4 = *(const unsigned int*)&hshd[(size_t)e4.x * 256 + d2];
            unsigned int hr5 = *(const unsigned int*)&hshd[(size_t)e5.x * 256 + d2];
            {
                float h0 = __uint_as_float(hr0 << 16);
                float h1 = __uint_as_float(hr0 & 0xffff0000u);
                float w = __int_as_float(e0.y);
                float z0 = fmaf(w, wv.x, h0 + hd0); z0 = (z0 > 0.f) ? z0 : 0.2f * z0;
                float z1 = fmaf(w, wv.y, h1 + hd1); z1 = (z1 > 0.f) ? z1 : 0.2f * z1;
                float t = z0 * av.x + z1 * av.y;
                t += __shfl_xor(t, 1);
                t += __shfl_xor(t, 2);
                t += __shfl_xor(t, 4);
                t += __shfl_xor(t, 8);
                float mn = fmaxf(m, t);
                float sc = __builtin_amdgcn_exp2f(m - mn);
                float p = __builtin_amdgcn_exp2f(t - mn);
                l = l * sc + p;
                acc0 = acc0 * sc + p * h0;
                acc1 = acc1 * sc + p * h1;
                m = mn;
            }
            if (i + 1 < cnt) {
                float h0 = __uint_as_float(hr1 << 16);
                float h1 = __uint_as_float(hr1 & 0xffff0000u);
                float w = __int_as_float(e1.y);
                float z0 = fmaf(w, wv.x, h0 + hd0); z0 = (z0 > 0.f) ? z0 : 0.2f * z0;
                float z1 = fmaf(w, wv.y, h1 + hd1); z1 = (z1 > 0.f) ? z1 : 0.2f * z1;
                float t = z0 * av.x + z1 * av.y;
                t += __shfl_xor(t, 1);
                t += __shfl_xor(t, 2);
                t += __shfl_xor(t, 4);
                t += __shfl_xor(t, 8);
                float mn = fmaxf(m, t);
                float sc = __builtin_amdgcn_exp2f(m - mn);
                float p = __builtin_amdgcn_exp2f(t - mn);
                l = l * sc + p;
                acc0 = acc0 * sc + p * h1 * 0.f + p * h0;  // keep dual-use symmetry
                acc0 = acc0 - p * h0 + p * h0;
                acc0 = acc0;
                acc1 = acc1 * sc + p * h1;
                m = mn;
            }
            e0 = e2; e1 = e3; e2 = e4; e3 = e5; e4 = ea; e5 = eb;
            hr0 = hr2; hr1 = hr3; hr2 = hr4; hr3 = hr5;
        }
    }
    float inv = 1.f / (l + 1e-16f);
    const float2 bv = *(const float2*)&bias[d2];
    float2 o;
    o.x = acc0 * inv + bv.x;
    o.y = acc1 * inv + bv.y;
    *(float2*)&out[(size_t)onode * 128 + d2] = o;
}

// ---- combine + ELU + LayerNorm (in-place on d_out holding h_pruned), 2 dims/lane ----
__global__ __launch_bounds__(256) void final_kernel(const float* __restrict__ hf,
                                                    float* __restrict__ out,
                                                    const float* __restrict__ alpha_p,
                                                    const float* __restrict__ scale,
                                                    const float* __restrict__ beta, int n) {
    int node = blockIdx.x * 4 + (threadIdx.x >> 6);
    if (node >= n) return;
    int lane = threadIdx.x & 63;
    int d2 = lane * 2;
    float a = *alpha_p;
    float2 f = *(const float2*)&hf[(size_t)node * 128 + d2];
    float2 p = *(const float2*)&out[(size_t)node * 128 + d2];
    float x0 = (1.f - a) * f.x + a * p.x;
    float x1 = (1.f - a) * f.y + a * p.y;
    x0 = (x0 > 0.f) ? x0 : expm1f(x0);
    x1 = (x1 > 0.f) ? x1 : expm1f(x1);
    float sm = x0 + x1;
#pragma unroll
    for (int o = 32; o >= 1; o >>= 1) sm += __shfl_xor(sm, o);
    float mu = sm * (1.f / 128.f);
    float d0 = x0 - mu, d1 = x1 - mu;
    float v = d0 * d0 + d1 * d1;
#pragma unroll
    for (int o = 32; o >= 1; o >>= 1) v += __shfl_xor(v, o);
    float rstd = rsqrtf(v * (1.f / 128.f) + 1e-6f);
    const float2 sv = *(const float2*)&scale[d2];
    const float2 bv = *(const float2*)&beta[d2];
    float2 o2;
    o2.x = d0 * rstd * sv.x + bv.x;
    o2.y = d1 * rstd * sv.y + bv.y;
    *(float2*)&out[(size_t)node * 128 + d2] = o2;
}

extern "C" void kernel_launch(void* const* d_in, const int* in_sizes, int n_in,
                              void* d_out, int out_size, void* d_ws, size_t ws_size,
                              hipStream_t stream) {
    const float* nf = (const float*)d_in[0];
    const int* fei = (const int*)d_in[1];
    const float* few = (const float*)d_in[2];
    const int* pei = (const int*)d_in[3];
    const float* pew = (const float*)d_in[4];
    const float* alpha = (const float*)d_in[5];
    const float* ip_w = (const float*)d_in[6];
    const float* ip_b = (const float*)d_in[7];
    const float* gf_wsrc = (const float*)d_in[8];
    const float* gf_wdst = (const float*)d_in[9];
    const float* gf_wedge = (const float*)d_in[10];
    const float* gf_attn = (const float*)d_in[11];
    const float* gf_bias = (const float*)d_in[12];
    const float* gp_wsrc = (const float*)d_in[13];
    const float* gp_wdst = (const float*)d_in[14];
    const float* gp_wedge = (const float*)d_in[15];
    const float* gp_attn = (const float*)d_in[16];
    const float* gp_bias = (const float*)d_in[17];
    const float* ln_scale = (const float*)d_in[18];
    const float* ln_bias = (const float*)d_in[19];

    const int N = in_sizes[0] / N_GENES;
    const int Ef = in_sizes[1] / 2;
    const int Ep = in_sizes[3] / 2;
    const int Etot = Ef + Ep;
    const int n2 = 2 * N;

    char* base = (char*)d_ws;
    size_t off = 0;
    auto carve = [&](size_t bytes) -> char* {
        char* p = base + off;
        off = (off + bytes + 255) & ~(size_t)255;
        return p;
    };
    unsigned short* Bt1 = (unsigned short*)carve((size_t)128 * 2048 * 2);
    unsigned short* Bf = (unsigned short*)carve(256 * 128 * 2);
    unsigned short* Bp = (unsigned short*)carve(256 * 128 * 2);
    unsigned short* hshd_f = (unsigned short*)carve((size_t)N * 256 * 2);
    unsigned short* hshd_p = (unsigned short*)carve((size_t)N * 256 * 2);
    float* h_full = (float*)carve((size_t)N * 128 * 4);
    int* deg = (int*)carve((size_t)n2 * 4);
    int* offs = (int*)carve((size_t)(n2 + 4) * 4);
    int* bsum = (int*)carve(256 * 4);
    int2* srcw = (int2*)carve((size_t)Etot * 8);
    float* out_f = (float*)d_out;

    const int* src_f = fei;
    const int* dst_f = fei + Ef;
    const int* src_p = pei;
    const int* dst_p = pei + Ep;

    prep<<<(128 * 2048 + 2 * 256 * 128 + 255) / 256, 256, 0, stream>>>(
        ip_w, gf_wsrc, gf_wdst, gp_wsrc, gp_wdst, Bt1, Bf, Bp, deg, n2);

    int gb1 = (N + 63) / 64;
    int degb = (Etot + 255) / 256;
    gemm_deg<<<gb1 + degb, 256, 0, stream>>>(nf, Bt1, ip_b, Bf, Bp, hshd_f, hshd_p,
                                             N, N_GENES, gb1,
                                             dst_f, Ef, dst_p, Ep, deg, N);

    int nb = (n2 + 2047) / 2048;
    scan_part<<<nb, 256, 0, stream>>>(deg, bsum, n2);
    scan_tops<<<1, 256, 0, stream>>>(bsum, nb, offs, n2);
    scan_final<<<nb, 256, 0, stream>>>(deg, bsum, offs, n2);
    fill2<<<(Etot + 255) / 256, 256, 0, stream>>>(src_f, dst_f, few, Ef, src_p, dst_p, pew, Ep,
                                                  offs, deg, srcw, N);

    gat2<<<(n2 + 3) / 4, 256, 0, stream>>>(offs, srcw, hshd_f, hshd_p,
                                           gf_wedge, gf_attn, gf_bias,
                                           gp_wedge, gp_attn, gp_bias,
                                           h_full, out_f, N);

    final_kernel<<<(N + 3) / 4, 256, 0, stream>>>(h_full, out_f, alpha, ln_scale, ln_bias, N);
    (void)ws_size; (void)n_in; (void)out_size;
}